// Round 3
// baseline (112.481 us; speedup 1.0000x reference)
//
#include <hip/hip_runtime.h>
#include <math.h>

// BIMM2D: M=250000 points, P=4 interior phases, K=6 interface pairs, N_MC=64
#define KN 384   // K * N_MC
#define NQ 96    // table entries per quarter-thread (KN/4)
#define TPB 256

typedef float v2f __attribute__((ext_vector_type(2)));

// Device-global scratch. g_ctr is module-init 0 and self-restored by the last
// block each launch -> graph-replay safe, independent of d_ws poison.
__device__ double g_part[2048];
__device__ int    g_ctr = 0;

__device__ __forceinline__ float fexp2(float x) {
#if __has_builtin(__builtin_amdgcn_exp2f)
  return __builtin_amdgcn_exp2f(x);   // native v_exp_f32
#else
  return exp2f(x);
#endif
}

// One fused kernel.
// Work decomposition: each thread owns ONE point-pair (i, i+H) and ONE quarter
// (96 interleaved entries) of the 384-entry (k,n) table. The 4 quarter-threads
// of a pair are lanes {p, p+16, p+32, p+48} of a wave; a butterfly
// __shfl_xor(16/32) combines them (bit-identical in all 4 lanes, so every lane
// adds 0.25x its copy -> deterministic). Quarter q also evaluates interior
// phase q. All exponentials are direct sums (args bounded, no max-shift), in
// exp2 form with the log2(e) factors pre-folded into the table.
__global__ __launch_bounds__(TPB) void fused_kernel(
    const float* __restrict__ u, const float* __restrict__ v,
    const float* __restrict__ eps, const float* __restrict__ I,
    const float* __restrict__ W, const float* __restrict__ sb_,
    const float* __restrict__ sn_, const float* __restrict__ d_,
    const float* __restrict__ r_, float* __restrict__ out,
    int M, int H, int nb) {
  __shared__ float4 stab[KN];
  __shared__ double red[TPB];
  __shared__ int    slast;
  const int tid  = threadIdx.x;
  const int lane = tid & 63;
  const int p    = lane & 15;        // pair slot within wave
  const int q    = (lane >> 4) & 3;  // quarter index
  const int gp   = blockIdx.x * 64 + (tid >> 6) * 16 + p;   // global pair id

  // hoist point loads to overlap with the prelude
  const bool act  = gp < H;
  const int  i1   = gp + H;
  const bool has1 = act && (i1 < M);
  float u0 = 0.f, v0 = 1.f, u1 = 0.f, v1 = 1.f;
  if (act)  { u0 = u[gp]; v0 = v[gp]; }
  if (has1) { u1 = u[i1]; v1 = v[i1]; }

  // ---- folded constants (uniform; float, faithful to f32 reference) ----
  const float sb  = sb_[0];
  const float sn  = sn_[0];
  const float dd  = d_[0];
  const float rho = tanhf(r_[0]);
  const float s2  = sn * sn * (1.f - rho);      // sr^2
  const float sr  = sqrtf(s2);
  const float isn = 1.f / sn;
  const float inv_s2 = 1.f / s2;
  const float LOG2E = 1.4426950408889634f;
  const float SQH   = sqrtf(0.5f * LOG2E);      // sqrt(0.5*log2 e)

  float wmax = W[0];
  for (int j = 1; j < 10; ++j) wmax = fmaxf(wmax, W[j]);
  float se = 0.f;
  for (int j = 0; j < 10; ++j) se += expf(W[j] - wmax);
  const float lse = wmax + logf(se);

  const float LOG2PI_ = 1.8378770664093453f;
  const float LOG2_   = 0.6931471805599453f;
  const float LGG32   = -0.12078223763524522f;  // log(gamma(1.5))
  const float LOGPI_  = 1.1447298858494002f;
  const float Cterm = -logf(sn) - 0.5f * LOG2PI_ - logf(sr) - 0.5f * LOGPI_;
  const float Cint0 = LOG2_ - LGG32 - 3.f * logf(sr) - logf(sn) - 0.5f * LOG2PI_;

  // interior phase q for this quarter-thread
  const float wq = expf(W[q] - lse + Cint0);
  const float cq = I[q] * isn * SQH;

  // ---- per-(k,n) table into LDS (exp2-folded) ----
  // stab[t] = { In/sn*SQH, (2G/s2)*log2e, wk*exp(-G^2/s2)/G, 0 }
  const int IAc[6] = {0, 0, 0, 1, 1, 2};
  const int IBc[6] = {1, 2, 3, 2, 3, 3};
  for (int t = tid; t < KN; t += TPB) {
    const int k = t >> 6;
    const float Ia = I[IAc[k]], Ib = I[IBc[k]];
    const float wk = expf(W[4 + k] - lse + Cterm) * (1.0f / 64.0f);
    const float e  = eps[t];
    const float x  = e * 2.f * dd * sb - dd * sb;
    const float y  = x / (1.4142135623730951f * sb);
    const float In = (erff(y) + 1.f) * 0.5f * (Ib - Ia) + Ia;
    const float qq = 2.f * (In - Ia) / (Ib - Ia) - 1.f;
    const float gi = erfinvf(qq);
    const float G  = (Ib - Ia) * 0.3989422804014327f / sb * expf(-gi * gi);
    float4 tt;
    tt.x = In * isn * SQH;
    tt.y = 2.f * inv_s2 * G * LOG2E;
    tt.z = wk * expf(-G * G * inv_s2) / G;
    tt.w = 0.f;
    stab[t] = tt;
  }
  __syncthreads();

  // ---- main: pair (i0,i1), quarter q of the table ----
  v2f T = {0.f, 0.f};
  if (act) {
    const v2f us = {u0 * isn * SQH, u1 * isn * SQH};
    const v2f vv = {v0, v1};

    // interior phase q (folds into the same reduction):
    // T += v * wq * exp2(-(us-cq)^2)
    {
      const v2f dq = us - cq;
      v2f ei;
      ei.x = fexp2(-dq.x * dq.x);
      ei.y = fexp2(-dq.y * dq.y);
      T = vv * (wq * ei);
    }

    // 96 interleaved entries: t = 4*nn + q  (distinct banks per quarter)
    const float4* tb = stab + q;
#pragma unroll 8
    for (int nn = 0; nn < NQ; ++nn) {
      const float4 tt = tb[nn * 4];
      const v2f z  = vv * tt.y;                            // z' = z*log2e
      const v2f du = us - tt.x;
      const v2f a1 = __builtin_elementwise_fma(du, -du, z);  //  z' - h'
      const v2f a2 = __builtin_elementwise_fma(du,  du, z);  //  z' + h'
      v2f e;
      e.x = fexp2(a1.x) - fexp2(-a2.x);
      e.y = fexp2(a1.y) - fexp2(-a2.y);
      T = __builtin_elementwise_fma(e, (v2f){tt.z, tt.z}, T);
    }
  }

  // butterfly combine over the 4 quarters (all lanes end bit-identical)
  T.x += __shfl_xor(T.x, 16, 64);
  T.y += __shfl_xor(T.y, 16, 64);
  T.x += __shfl_xor(T.x, 32, 64);
  T.y += __shfl_xor(T.y, 32, 64);

  double mysum = 0.0;
  if (act) {
    const float g0 = __expf(-v0 * v0 * inv_s2);
    const float acc0 = v0 * g0 * T.x;
    mysum = (double)__logf(acc0);
    if (has1) {
      const float g1 = __expf(-v1 * v1 * inv_s2);
      const float acc1 = v1 * g1 * T.y;
      mysum += (double)__logf(acc1);
    }
    mysum *= 0.25;   // 4 quarter-lanes hold identical copies (exact scale)
  }

  // ---- block reduction ----
  red[tid] = mysum;
  __syncthreads();
  for (int s = TPB / 2; s > 0; s >>= 1) {
    if (tid < s) red[tid] += red[tid + s];
    __syncthreads();
  }
  if (tid == 0)
    __hip_atomic_store(&g_part[blockIdx.x], red[0], __ATOMIC_RELAXED,
                       __HIP_MEMORY_SCOPE_AGENT);

  // ---- last-block-done final reduction (fixed order -> deterministic) ----
  if (tid == 0) {
    const int c = __hip_atomic_fetch_add(&g_ctr, 1, __ATOMIC_ACQ_REL,
                                         __HIP_MEMORY_SCOPE_AGENT);
    slast = (c == nb - 1) ? 1 : 0;
  }
  __syncthreads();
  if (slast) {
    double s = 0.0;
    for (int j = tid; j < nb; j += TPB)
      s += __hip_atomic_load(&g_part[j], __ATOMIC_RELAXED,
                             __HIP_MEMORY_SCOPE_AGENT);
    red[tid] = s;
    __syncthreads();
    for (int k2 = TPB / 2; k2 > 0; k2 >>= 1) {
      if (tid < k2) red[tid] += red[tid + k2];
      __syncthreads();
    }
    if (tid == 0) {
      out[0] = (float)(-red[0] / (double)M);
      __hip_atomic_store(&g_ctr, 0, __ATOMIC_RELAXED,
                         __HIP_MEMORY_SCOPE_AGENT);  // restore for next replay
    }
  }
}

extern "C" void kernel_launch(void* const* d_in, const int* in_sizes, int n_in,
                              void* d_out, int out_size, void* d_ws, size_t ws_size,
                              hipStream_t stream) {
  const float* u   = (const float*)d_in[0];
  const float* v   = (const float*)d_in[1];
  const float* eps = (const float*)d_in[2];
  const float* I   = (const float*)d_in[3];
  const float* W   = (const float*)d_in[4];
  const float* sb  = (const float*)d_in[5];
  const float* sn  = (const float*)d_in[6];
  const float* dd  = (const float*)d_in[7];
  const float* r   = (const float*)d_in[8];
  const int M  = in_sizes[0];
  const int H  = (M + 1) / 2;                 // pairs (i, i+H)
  const int nb = (H + 63) / 64;               // 64 pairs per block -> 1954
  hipLaunchKernelGGL(fused_kernel, dim3(nb), dim3(TPB), 0, stream,
                     u, v, eps, I, W, sb, sn, dd, r, (float*)d_out, M, H, nb);
}